// Round 6
// baseline (431.380 us; speedup 1.0000x reference)
//
#include <hip/hip_runtime.h>

constexpr int B = 2;
constexpr int N = 50000;
constexpr int D = 64;
constexpr int E = 800000;
constexpr int CAP = 96;      // Poisson(32) max over 50k nodes ~58; 96 = huge margin
constexpr int XG = 8;        // XCD groups
constexpr int NPG = N / XG;  // 6250 nodes per group
constexpr int GBLK = N / 4;  // 12500 gather blocks per phase

// ---- bf16 helpers (manual RTN) --------------------------------------------
__device__ __forceinline__ unsigned f2bf(float f) {
    unsigned u = __float_as_uint(f);
    return (u + 0x7FFFu + ((u >> 16) & 1u)) >> 16;
}
__device__ __forceinline__ float bfhi2f(unsigned bits) {
    return __uint_as_float(bits & 0xFFFF0000u);
}
__device__ __forceinline__ float bflo2f(unsigned bits) {
    return __uint_as_float(bits << 16);
}

// ===========================================================================
// 1) P = prev @ W^T  (per row: P[row,i] = sum_d prev[row,d]*W[i,d]), bf16-
// packed: P32[row*32 + j] holds features {2j, 2j+1}. fp32 math, round once.
// ===========================================================================
__global__ __launch_bounds__(256) void pgemm_kernel(
    const float* __restrict__ prev,
    const float* __restrict__ W,
    unsigned* __restrict__ P32)
{
    __shared__ float Wl[D][D + 1];   // lane i reads Wl[i][d]: 2-way alias, free
    __shared__ float xs[4][D];

    int t = threadIdx.x;
    for (int i = t; i < D * D; i += 256) Wl[i >> 6][i & 63] = W[i];

    int wave = t >> 6, lane = t & 63;
    size_t row = (size_t)blockIdx.x * 4 + wave;   // grid = B*N/4 = 25000 exact

    xs[wave][lane] = prev[row * D + lane];
    __syncthreads();

    float acc = 0.f;
#pragma unroll
    for (int d = 0; d < D; ++d) acc += xs[wave][d] * Wl[lane][d];

    float partner = __shfl_xor(acc, 1, 64);       // feature lane^1
    if ((lane & 1) == 0) {
        P32[row * 32 + (lane >> 1)] = f2bf(acc) | (f2bf(partner) << 16);
    }
}

// ===========================================================================
// 2) XCD-partitioned slot build (unchanged from round 5).
// entry = (g_bf16 << 16) | neighbor
// ===========================================================================
__global__ __launch_bounds__(256) void build_kernel(
    const int2* __restrict__ edges, const float* __restrict__ status,
    int* __restrict__ counts, unsigned* __restrict__ slots)
{
    int g = blockIdx.x & 7;
    int e = (blockIdx.x >> 3) * 256 + threadIdx.x;  // grid = (E/256)*8
    if (e >= E) return;
    int2 uv = edges[e];
    unsigned gb = f2bf(status[e]) << 16;
    if (uv.x / NPG == g) {
        int p = atomicAdd(&counts[uv.x], 1);
        if (p < CAP) slots[(size_t)uv.x * CAP + p] = gb | (unsigned)uv.y;
    }
    if (uv.y / NPG == g) {
        int p = atomicAdd(&counts[uv.y], 1);
        if (p < CAP) slots[(size_t)uv.y * CAP + p] = gb | (unsigned)uv.x;
    }
}

// ===========================================================================
// 3) Phase-tiled gather: phase = (batch b, feature-half h). Per phase the
// active P slice is 50k x 64 B = 3.2 MB -> L2-resident per XCD. Wave = node;
// 4 subs x 16 lanes walk entries 4-wide; per entry ONE 64 B row load.
// Output is final: leaky_relu(node + gathered_P + edgef).
// ===========================================================================
__global__ __launch_bounds__(256) void gather_out(
    const unsigned* __restrict__ P32,
    const int* __restrict__ counts,
    const unsigned* __restrict__ slots,
    const float2* __restrict__ node2,
    const float2* __restrict__ edgef2,
    float2* __restrict__ out2)
{
    int pid = blockIdx.x;                  // grid = 4 * GBLK, in dispatch order
    int phase = pid / GBLK;
    int nblk = pid - phase * GBLK;
    int b = phase >> 1, h = phase & 1;

    int wave = threadIdx.x >> 6, lane = threadIdx.x & 63;
    int n = nblk * 4 + wave;
    int q = lane & 15, sub = lane >> 4;

    int cnt = min(counts[n], CAP);
    size_t sbase = (size_t)n * CAP;
    const unsigned* Pb = P32 + (size_t)b * N * 32 + 16 * h + q;

    float a0 = 0.f, a1 = 0.f;
    for (int k = sub; k < cnt; k += 4) {
        unsigned ent = slots[sbase + k];   // broadcast within 16-lane sub
        float g = bfhi2f(ent);
        unsigned nb = ent & 0xFFFFu;
        unsigned r = Pb[(size_t)nb * 32];  // 16 lanes x 4 B = one 64 B line
        a0 += g * bflo2f(r);
        a1 += g * bfhi2f(r);
    }

    a0 += __shfl_xor(a0, 16, 64); a0 += __shfl_xor(a0, 32, 64);
    a1 += __shfl_xor(a1, 16, 64); a1 += __shfl_xor(a1, 32, 64);

    if (sub == 0) {
        size_t o = ((size_t)b * N + n) * 32 + 16 * h + q;  // float2 index
        float2 nd = node2[o], ef = edgef2[o];
        float y0 = nd.x + a0 + ef.x;
        float y1 = nd.y + a1 + ef.y;
        out2[o] = make_float2((y0 >= 0.f) ? y0 : 0.01f * y0,
                              (y1 >= 0.f) ? y1 : 0.01f * y1);
    }
}

// ===========================================================================
// LAST-RESORT FALLBACK (tiny ws): atomic scatter + separate gemm (fp32 exact)
// ===========================================================================
__device__ inline void atomic_add4(float* p, float4 val, float g) {
    atomicAdd(p + 0, val.x * g);
    atomicAdd(p + 1, val.y * g);
    atomicAdd(p + 2, val.z * g);
    atomicAdd(p + 3, val.w * g);
}

__global__ __launch_bounds__(256) void scatter_kernel(
    const float* __restrict__ prev,
    const int2* __restrict__ edges,
    const float* __restrict__ status,
    float* __restrict__ nbr)
{
    int idx = blockIdx.x * 256 + threadIdx.x;
    int e = idx >> 4;
    int q = idx & 15;
    if (e >= E) return;
    int2 uv = edges[e];
    float g = status[e];
    const float4* p0 = (const float4*)prev;
    const float4* p1 = (const float4*)(prev + (size_t)N * D);
    float4 pu0 = p0[(size_t)uv.x * 16 + q];
    float4 pv0 = p0[(size_t)uv.y * 16 + q];
    float4 pu1 = p1[(size_t)uv.x * 16 + q];
    float4 pv1 = p1[(size_t)uv.y * 16 + q];
    float* n0 = nbr;
    float* n1 = nbr + (size_t)N * D;
    int off_v = uv.y * D + q * 4;
    int off_u = uv.x * D + q * 4;
    atomic_add4(n0 + off_v, pu0, g);
    atomic_add4(n0 + off_u, pv0, g);
    atomic_add4(n1 + off_v, pu1, g);
    atomic_add4(n1 + off_u, pv1, g);
}

__global__ __launch_bounds__(256) void gemm_relu_kernel(
    float* __restrict__ out,
    const float* __restrict__ node,
    const float* __restrict__ edgef,
    const float* __restrict__ W)
{
    __shared__ float Wl[D][D + 1];
    __shared__ float xs[4][D];
    int t = threadIdx.x;
    for (int i = t; i < D * D; i += 256) Wl[i >> 6][i & 63] = W[i];
    int wave = t >> 6, lane = t & 63;
    int row = blockIdx.x * 4 + wave;
    size_t base = (size_t)row * D;
    float x = out[base + lane];
    xs[wave][lane] = x;
    __syncthreads();
    float acc = 0.f;
#pragma unroll
    for (int d = 0; d < D; ++d) acc += xs[wave][d] * Wl[lane][d];
    float y = node[base + lane] + acc + edgef[base + lane];
    out[base + lane] = (y >= 0.f) ? y : 0.01f * y;
}

// ===========================================================================
extern "C" void kernel_launch(void* const* d_in, const int* in_sizes, int n_in,
                              void* d_out, int out_size, void* d_ws, size_t ws_size,
                              hipStream_t stream) {
    const float* prev   = (const float*)d_in[0];
    const int*   edges  = (const int*)d_in[1];
    const float* node   = (const float*)d_in[2];
    const float* edgef  = (const float*)d_in[3];
    const float* status = (const float*)d_in[4];
    const float* W      = (const float*)d_in[5];
    float* out = (float*)d_out;

    const int2* edges2 = (const int2*)edges;

    // ws: slots[N*CAP] u32 | counts[N] i32 | P32[B*N*32] u32
    size_t slots_bytes  = (size_t)N * CAP * sizeof(unsigned);   // 19.2 MB
    size_t counts_bytes = (size_t)N * sizeof(int);              // 0.2 MB
    size_t p_bytes      = (size_t)B * N * 32 * sizeof(unsigned);// 12.8 MB
    size_t need = slots_bytes + counts_bytes + p_bytes;

    if (ws_size >= need) {
        unsigned* slots = (unsigned*)d_ws;
        int* counts = (int*)((char*)d_ws + slots_bytes);
        unsigned* P32 = (unsigned*)((char*)d_ws + slots_bytes + counts_bytes);

        hipMemsetAsync(counts, 0, counts_bytes, stream);
        pgemm_kernel<<<(B * N) / 4, 256, 0, stream>>>(prev, W, P32);
        build_kernel<<<(E / 256) * XG, 256, 0, stream>>>(
            edges2, status, counts, slots);
        gather_out<<<4 * GBLK, 256, 0, stream>>>(
            P32, counts, slots, (const float2*)node, (const float2*)edgef,
            (float2*)out);
    } else {
        hipMemsetAsync(out, 0, (size_t)B * N * D * sizeof(float), stream);
        scatter_kernel<<<(E * 16) / 256, 256, 0, stream>>>(prev, edges2, status, out);
        gemm_relu_kernel<<<(B * N) / 4, 256, 0, stream>>>(out, node, edgef, W);
    }
}

// Round 7
// 326.514 us; speedup vs baseline: 1.3212x; 1.3212x over previous
//
#include <hip/hip_runtime.h>

constexpr int B = 2;
constexpr int N = 50000;
constexpr int D = 64;
constexpr int E = 800000;
constexpr int CAP = 96;      // Poisson(32) max degree over 50k nodes ~58; 96 = margin
constexpr int XG = 8;        // XCD groups
constexpr int NPG = N / XG;  // 6250 nodes per group

// ---- bf16 helpers (manual RTN) --------------------------------------------
__device__ __forceinline__ unsigned f2bf(float f) {
    unsigned u = __float_as_uint(f);
    return (u + 0x7FFFu + ((u >> 16) & 1u)) >> 16;
}
__device__ __forceinline__ float bfhi2f(unsigned bits) {
    return __uint_as_float(bits & 0xFFFF0000u);
}
__device__ __forceinline__ float bflo2f(unsigned bits) {
    return __uint_as_float(bits << 16);
}

// ===========================================================================
// 1) P = prev @ W^T, bf16-packed: P32[row*32+p] = features {2p, 2p+1}.
// Also zeroes counts[] (2 ints per block) -- replaces the memset dispatch.
// ===========================================================================
__global__ __launch_bounds__(256) void pgemm_kernel(
    const float* __restrict__ prev,
    const float* __restrict__ W,
    unsigned* __restrict__ P32,
    int* __restrict__ counts)
{
    __shared__ float Wl[D][D + 1];   // lane i reads Wl[i][d]: 2-way alias, free
    __shared__ float xs[4][D];

    int t = threadIdx.x;
    // zero counts: grid = 25000 blocks x 2 ints = 50000 = N exactly
    if (t < 2) counts[blockIdx.x * 2 + t] = 0;

    for (int i = t; i < D * D; i += 256) Wl[i >> 6][i & 63] = W[i];

    int wave = t >> 6, lane = t & 63;
    size_t row = (size_t)blockIdx.x * 4 + wave;   // grid = B*N/4 = 25000 exact

    xs[wave][lane] = prev[row * D + lane];
    __syncthreads();

    float acc = 0.f;
#pragma unroll
    for (int d = 0; d < D; ++d) acc += xs[wave][d] * Wl[lane][d];

    float partner = __shfl_xor(acc, 1, 64);       // feature lane^1
    if ((lane & 1) == 0) {
        P32[row * 32 + (lane >> 1)] = f2bf(acc) | (f2bf(partner) << 16);
    }
}

// ===========================================================================
// 2) XCD-partitioned slot build. Replica g = blockIdx&7 writes only endpoints
// with node/NPG == g (round-robin blockIdx->XCD keeps a node's slot lines
// written from one XCD -> partial 64B lines merge in its L2).
// entry = (g_bf16 << 16) | neighbor
// ===========================================================================
__global__ __launch_bounds__(256) void build_kernel(
    const int2* __restrict__ edges, const float* __restrict__ status,
    int* __restrict__ counts, unsigned* __restrict__ slots)
{
    int g = blockIdx.x & 7;
    int e = (blockIdx.x >> 3) * 256 + threadIdx.x;  // grid = (E/256)*8
    if (e >= E) return;
    int2 uv = edges[e];
    unsigned gb = f2bf(status[e]) << 16;
    if (uv.x / NPG == g) {
        int p = atomicAdd(&counts[uv.x], 1);
        if (p < CAP) slots[(size_t)uv.x * CAP + p] = gb | (unsigned)uv.y;
    }
    if (uv.y / NPG == g) {
        int p = atomicAdd(&counts[uv.y], 1);
        if (p < CAP) slots[(size_t)uv.y * CAP + p] = gb | (unsigned)uv.x;
    }
}

// ===========================================================================
// 3) Single-pass gather of P rows, final output directly.
// Wave = node (both batches). 8 subs x 8 lanes; sub s walks entries s, s+8,...
// Per entry: 2 x uint4 loads (128 B/batch) -> 2 KB in flight per wave-iter.
// Reduce across subs via shfl_xor; bounce row through per-wave LDS (no
// barrier: same-wave visibility) so all 64 lanes do the coalesced epilogue.
// ===========================================================================
__global__ __launch_bounds__(256) void gather_final(
    const uint4* __restrict__ P4,     // (B*N, 8) uint4 rows
    const int* __restrict__ counts,
    const unsigned* __restrict__ slots,
    const float* __restrict__ node,
    const float* __restrict__ edgef,
    float* __restrict__ out)
{
    __shared__ float xs[4][2][D];

    int t = threadIdx.x;
    int wave = t >> 6, lane = t & 63;
    int n = blockIdx.x * 4 + wave;    // grid = N/4 = 12500 exact
    int j = lane & 7;                 // uint4 chunk within row (8 x 16 B)
    int sub = lane >> 3;              // 8-wide entry parallelism

    int cnt = min(counts[n], CAP);
    size_t sbase = (size_t)n * CAP;

    float a0[8], a1[8];
#pragma unroll
    for (int i = 0; i < 8; ++i) { a0[i] = 0.f; a1[i] = 0.f; }

    for (int k = sub; k < cnt; k += 8) {
        unsigned ent = slots[sbase + k];          // broadcast within 8-lane sub
        float g = bfhi2f(ent);
        unsigned nb = ent & 0xFFFFu;
        uint4 r0 = P4[(size_t)nb * 8 + j];                 // batch 0 row chunk
        uint4 r1 = P4[((size_t)N + nb) * 8 + j];           // batch 1 row chunk
        a0[0] += g * bflo2f(r0.x); a0[1] += g * bfhi2f(r0.x);
        a0[2] += g * bflo2f(r0.y); a0[3] += g * bfhi2f(r0.y);
        a0[4] += g * bflo2f(r0.z); a0[5] += g * bfhi2f(r0.z);
        a0[6] += g * bflo2f(r0.w); a0[7] += g * bfhi2f(r0.w);
        a1[0] += g * bflo2f(r1.x); a1[1] += g * bfhi2f(r1.x);
        a1[2] += g * bflo2f(r1.y); a1[3] += g * bfhi2f(r1.y);
        a1[4] += g * bflo2f(r1.z); a1[5] += g * bfhi2f(r1.z);
        a1[6] += g * bflo2f(r1.w); a1[7] += g * bfhi2f(r1.w);
    }

    // reduce the 8 subgroups (lane bits 3,4,5)
#pragma unroll
    for (int m = 8; m <= 32; m <<= 1) {
#pragma unroll
        for (int i = 0; i < 8; ++i) {
            a0[i] += __shfl_xor(a0[i], m, 64);
            a1[i] += __shfl_xor(a1[i], m, 64);
        }
    }

    // lanes 0..7 (sub 0) deposit the reduced row into per-wave LDS
    if (sub == 0) {
        *(float4*)&xs[wave][0][j * 8]     = make_float4(a0[0], a0[1], a0[2], a0[3]);
        *(float4*)&xs[wave][0][j * 8 + 4] = make_float4(a0[4], a0[5], a0[6], a0[7]);
        *(float4*)&xs[wave][1][j * 8]     = make_float4(a1[0], a1[1], a1[2], a1[3]);
        *(float4*)&xs[wave][1][j * 8 + 4] = make_float4(a1[4], a1[5], a1[6], a1[7]);
    }
    // same-wave LDS dependence: compiler inserts lgkmcnt wait; no barrier.
    float s0 = xs[wave][0][lane];
    float s1 = xs[wave][1][lane];

    size_t b0 = (size_t)n * D + lane;
    size_t b1 = (size_t)N * D + b0;
    float y0 = node[b0] + s0 + edgef[b0];
    float y1 = node[b1] + s1 + edgef[b1];
    out[b0] = (y0 >= 0.f) ? y0 : 0.01f * y0;
    out[b1] = (y1 >= 0.f) ? y1 : 0.01f * y1;
}

// ===========================================================================
// LAST-RESORT FALLBACK (tiny ws): atomic scatter + separate gemm (fp32 exact)
// ===========================================================================
__device__ inline void atomic_add4(float* p, float4 val, float g) {
    atomicAdd(p + 0, val.x * g);
    atomicAdd(p + 1, val.y * g);
    atomicAdd(p + 2, val.z * g);
    atomicAdd(p + 3, val.w * g);
}

__global__ __launch_bounds__(256) void scatter_kernel(
    const float* __restrict__ prev,
    const int2* __restrict__ edges,
    const float* __restrict__ status,
    float* __restrict__ nbr)
{
    int idx = blockIdx.x * 256 + threadIdx.x;
    int e = idx >> 4;
    int q = idx & 15;
    if (e >= E) return;
    int2 uv = edges[e];
    float g = status[e];
    const float4* p0 = (const float4*)prev;
    const float4* p1 = (const float4*)(prev + (size_t)N * D);
    float4 pu0 = p0[(size_t)uv.x * 16 + q];
    float4 pv0 = p0[(size_t)uv.y * 16 + q];
    float4 pu1 = p1[(size_t)uv.x * 16 + q];
    float4 pv1 = p1[(size_t)uv.y * 16 + q];
    float* n0 = nbr;
    float* n1 = nbr + (size_t)N * D;
    int off_v = uv.y * D + q * 4;
    int off_u = uv.x * D + q * 4;
    atomic_add4(n0 + off_v, pu0, g);
    atomic_add4(n0 + off_u, pv0, g);
    atomic_add4(n1 + off_v, pu1, g);
    atomic_add4(n1 + off_u, pv1, g);
}

__global__ __launch_bounds__(256) void gemm_relu_kernel(
    float* __restrict__ out,
    const float* __restrict__ node,
    const float* __restrict__ edgef,
    const float* __restrict__ W)
{
    __shared__ float Wl[D][D + 1];
    __shared__ float xs[4][D];
    int t = threadIdx.x;
    for (int i = t; i < D * D; i += 256) Wl[i >> 6][i & 63] = W[i];
    int wave = t >> 6, lane = t & 63;
    int row = blockIdx.x * 4 + wave;
    size_t base = (size_t)row * D;
    float x = out[base + lane];
    xs[wave][lane] = x;
    __syncthreads();
    float acc = 0.f;
#pragma unroll
    for (int d = 0; d < D; ++d) acc += xs[wave][d] * Wl[lane][d];
    float y = node[base + lane] + acc + edgef[base + lane];
    out[base + lane] = (y >= 0.f) ? y : 0.01f * y;
}

// ===========================================================================
extern "C" void kernel_launch(void* const* d_in, const int* in_sizes, int n_in,
                              void* d_out, int out_size, void* d_ws, size_t ws_size,
                              hipStream_t stream) {
    const float* prev   = (const float*)d_in[0];
    const int*   edges  = (const int*)d_in[1];
    const float* node   = (const float*)d_in[2];
    const float* edgef  = (const float*)d_in[3];
    const float* status = (const float*)d_in[4];
    const float* W      = (const float*)d_in[5];
    float* out = (float*)d_out;

    const int2* edges2 = (const int2*)edges;

    // ws: slots[N*CAP] u32 | counts[N] i32 | P32[B*N*32] u32
    size_t slots_bytes  = (size_t)N * CAP * sizeof(unsigned);    // 19.2 MB
    size_t counts_bytes = (size_t)N * sizeof(int);               // 0.2 MB
    size_t p_bytes      = (size_t)B * N * 32 * sizeof(unsigned); // 12.8 MB
    size_t need = slots_bytes + counts_bytes + p_bytes;

    if (ws_size >= need) {
        unsigned* slots = (unsigned*)d_ws;
        int* counts = (int*)((char*)d_ws + slots_bytes);
        unsigned* P32 = (unsigned*)((char*)d_ws + slots_bytes + counts_bytes);

        pgemm_kernel<<<(B * N) / 4, 256, 0, stream>>>(prev, W, P32, counts);
        build_kernel<<<(E / 256) * XG, 256, 0, stream>>>(
            edges2, status, counts, slots);
        gather_final<<<N / 4, 256, 0, stream>>>(
            (const uint4*)P32, counts, slots, node, edgef, out);
    } else {
        hipMemsetAsync(out, 0, (size_t)B * N * D * sizeof(float), stream);
        scatter_kernel<<<(E * 16) / 256, 256, 0, stream>>>(prev, edges2, status, out);
        gemm_relu_kernel<<<(B * N) / 4, 256, 0, stream>>>(out, node, edgef, W);
    }
}

// Round 8
// 300.263 us; speedup vs baseline: 1.4367x; 1.0874x over previous
//
#include <hip/hip_runtime.h>

constexpr int B = 2;
constexpr int N = 50000;
constexpr int D = 64;
constexpr int E = 800000;
constexpr int CAP = 96;        // Poisson(32) max degree over 50k nodes ~58; 96 = margin
constexpr int XG = 8;          // XCD groups
constexpr int NPG = N / XG;    // 6250 nodes per group
constexpr int ECHUNKS = E / 256;          // 3125 build chunks (x8 replicas = 25000 blocks)
constexpr int PBLOCKS = (B * N) / 4;      // 25000 pgemm blocks

// ---- bf16 helpers (manual RTN) --------------------------------------------
__device__ __forceinline__ unsigned f2bf(float f) {
    unsigned u = __float_as_uint(f);
    return (u + 0x7FFFu + ((u >> 16) & 1u)) >> 16;
}
__device__ __forceinline__ float bfhi2f(unsigned bits) {
    return __uint_as_float(bits & 0xFFFF0000u);
}
__device__ __forceinline__ float bflo2f(unsigned bits) {
    return __uint_as_float(bits << 16);
}

// ===========================================================================
// 1) FUSED build + pgemm, one dispatch, 50000 blocks in groups of 8:
//    even groups -> XCD-partitioned slot build (g = blockIdx&7 == XCD id,
//    preserved because interleaving granularity is 8);
//    odd groups  -> P = prev @ W^T rows (bf16-packed), LDS-light inner loop
//    (prev row via wave-uniform s_load, W row via single ds_read).
// Build blocks are atomic/latency-bound (VALU idle); pgemm blocks are
// VALU/LDS-bound -> co-resident overlap, time ~= max not sum.
// ===========================================================================
__global__ __launch_bounds__(256) void build_pgemm_fused(
    const int2* __restrict__ edges, const float* __restrict__ status,
    int* __restrict__ counts, unsigned* __restrict__ slots,
    const float* __restrict__ prev, const float* __restrict__ W,
    unsigned* __restrict__ P32)
{
    __shared__ float Wl[D][D + 1];   // lane i reads Wl[i][d]: 2-way alias, free

    int grp = blockIdx.x >> 3;
    int sub8 = blockIdx.x & 7;
    int t = threadIdx.x;

    if ((grp & 1) == 0) {
        // ---- build replica: chunk = grp/2 in [0,3125), replica g = sub8 ----
        int e = (grp >> 1) * 256 + t;             // < E always (3125*256 == E)
        int2 uv = edges[e];
        unsigned gb = f2bf(status[e]) << 16;
        if (uv.x / NPG == sub8) {
            int p = atomicAdd(&counts[uv.x], 1);
            if (p < CAP) slots[(size_t)uv.x * CAP + p] = gb | (unsigned)uv.y;
        }
        if (uv.y / NPG == sub8) {
            int p = atomicAdd(&counts[uv.y], 1);
            if (p < CAP) slots[(size_t)uv.y * CAP + p] = gb | (unsigned)uv.x;
        }
    } else {
        // ---- pgemm: block pb in [0,25000), 4 rows, wave = row --------------
        int pb = (grp >> 1) * 8 + sub8;
        for (int i = t; i < D * D; i += 256) Wl[i >> 6][i & 63] = W[i];
        __syncthreads();

        int wave = t >> 6, lane = t & 63;
        int row = __builtin_amdgcn_readfirstlane(pb * 4 + wave);
        const float* pr = prev + (size_t)row * D;   // wave-uniform -> s_load

        float acc = 0.f;
#pragma unroll
        for (int d = 0; d < D; ++d) acc += pr[d] * Wl[lane][d];

        float partner = __shfl_xor(acc, 1, 64);     // feature lane^1
        if ((lane & 1) == 0) {
            P32[(size_t)row * 32 + (lane >> 1)] = f2bf(acc) | (f2bf(partner) << 16);
        }
    }
}

// ===========================================================================
// 2) Single-pass gather of P rows -> final output (round-7 structure).
// Wave = node (both batches). 8 subs x 8 lanes; per entry 2 x uint4 loads
// (128 B/batch). shfl-reduce across subs; LDS bounce for coalesced epilogue.
// ===========================================================================
__global__ __launch_bounds__(256) void gather_final(
    const uint4* __restrict__ P4,     // (B*N, 8) uint4 rows
    const int* __restrict__ counts,
    const unsigned* __restrict__ slots,
    const float* __restrict__ node,
    const float* __restrict__ edgef,
    float* __restrict__ out)
{
    __shared__ float xs[4][2][D];

    int t = threadIdx.x;
    int wave = t >> 6, lane = t & 63;
    int n = blockIdx.x * 4 + wave;    // grid = N/4 = 12500 exact
    int j = lane & 7;                 // uint4 chunk within row
    int sub = lane >> 3;              // 8-wide entry parallelism

    int cnt = min(counts[n], CAP);
    size_t sbase = (size_t)n * CAP;

    float a0[8], a1[8];
#pragma unroll
    for (int i = 0; i < 8; ++i) { a0[i] = 0.f; a1[i] = 0.f; }

    for (int k = sub; k < cnt; k += 8) {
        unsigned ent = slots[sbase + k];
        float g = bfhi2f(ent);
        unsigned nb = ent & 0xFFFFu;
        uint4 r0 = P4[(size_t)nb * 8 + j];
        uint4 r1 = P4[((size_t)N + nb) * 8 + j];
        a0[0] += g * bflo2f(r0.x); a0[1] += g * bfhi2f(r0.x);
        a0[2] += g * bflo2f(r0.y); a0[3] += g * bfhi2f(r0.y);
        a0[4] += g * bflo2f(r0.z); a0[5] += g * bfhi2f(r0.z);
        a0[6] += g * bflo2f(r0.w); a0[7] += g * bfhi2f(r0.w);
        a1[0] += g * bflo2f(r1.x); a1[1] += g * bfhi2f(r1.x);
        a1[2] += g * bflo2f(r1.y); a1[3] += g * bfhi2f(r1.y);
        a1[4] += g * bflo2f(r1.z); a1[5] += g * bfhi2f(r1.z);
        a1[6] += g * bflo2f(r1.w); a1[7] += g * bfhi2f(r1.w);
    }

#pragma unroll
    for (int m = 8; m <= 32; m <<= 1) {
#pragma unroll
        for (int i = 0; i < 8; ++i) {
            a0[i] += __shfl_xor(a0[i], m, 64);
            a1[i] += __shfl_xor(a1[i], m, 64);
        }
    }

    if (sub == 0) {
        *(float4*)&xs[wave][0][j * 8]     = make_float4(a0[0], a0[1], a0[2], a0[3]);
        *(float4*)&xs[wave][0][j * 8 + 4] = make_float4(a0[4], a0[5], a0[6], a0[7]);
        *(float4*)&xs[wave][1][j * 8]     = make_float4(a1[0], a1[1], a1[2], a1[3]);
        *(float4*)&xs[wave][1][j * 8 + 4] = make_float4(a1[4], a1[5], a1[6], a1[7]);
    }
    // same-wave LDS dependence: compiler inserts lgkmcnt wait; no barrier.
    float s0 = xs[wave][0][lane];
    float s1 = xs[wave][1][lane];

    size_t b0 = (size_t)n * D + lane;
    size_t b1 = (size_t)N * D + b0;
    float y0 = node[b0] + s0 + edgef[b0];
    float y1 = node[b1] + s1 + edgef[b1];
    out[b0] = (y0 >= 0.f) ? y0 : 0.01f * y0;
    out[b1] = (y1 >= 0.f) ? y1 : 0.01f * y1;
}

// ===========================================================================
// LAST-RESORT FALLBACK (tiny ws): atomic scatter + separate gemm (fp32 exact)
// ===========================================================================
__device__ inline void atomic_add4(float* p, float4 val, float g) {
    atomicAdd(p + 0, val.x * g);
    atomicAdd(p + 1, val.y * g);
    atomicAdd(p + 2, val.z * g);
    atomicAdd(p + 3, val.w * g);
}

__global__ __launch_bounds__(256) void scatter_kernel(
    const float* __restrict__ prev,
    const int2* __restrict__ edges,
    const float* __restrict__ status,
    float* __restrict__ nbr)
{
    int idx = blockIdx.x * 256 + threadIdx.x;
    int e = idx >> 4;
    int q = idx & 15;
    if (e >= E) return;
    int2 uv = edges[e];
    float g = status[e];
    const float4* p0 = (const float4*)prev;
    const float4* p1 = (const float4*)(prev + (size_t)N * D);
    float4 pu0 = p0[(size_t)uv.x * 16 + q];
    float4 pv0 = p0[(size_t)uv.y * 16 + q];
    float4 pu1 = p1[(size_t)uv.x * 16 + q];
    float4 pv1 = p1[(size_t)uv.y * 16 + q];
    float* n0 = nbr;
    float* n1 = nbr + (size_t)N * D;
    int off_v = uv.y * D + q * 4;
    int off_u = uv.x * D + q * 4;
    atomic_add4(n0 + off_v, pu0, g);
    atomic_add4(n0 + off_u, pv0, g);
    atomic_add4(n1 + off_v, pu1, g);
    atomic_add4(n1 + off_u, pv1, g);
}

__global__ __launch_bounds__(256) void gemm_relu_kernel(
    float* __restrict__ out,
    const float* __restrict__ node,
    const float* __restrict__ edgef,
    const float* __restrict__ W)
{
    __shared__ float Wl[D][D + 1];
    __shared__ float xs[4][D];
    int t = threadIdx.x;
    for (int i = t; i < D * D; i += 256) Wl[i >> 6][i & 63] = W[i];
    int wave = t >> 6, lane = t & 63;
    int row = blockIdx.x * 4 + wave;
    size_t base = (size_t)row * D;
    float x = out[base + lane];
    xs[wave][lane] = x;
    __syncthreads();
    float acc = 0.f;
#pragma unroll
    for (int d = 0; d < D; ++d) acc += xs[wave][d] * Wl[lane][d];
    float y = node[base + lane] + acc + edgef[base + lane];
    out[base + lane] = (y >= 0.f) ? y : 0.01f * y;
}

// ===========================================================================
extern "C" void kernel_launch(void* const* d_in, const int* in_sizes, int n_in,
                              void* d_out, int out_size, void* d_ws, size_t ws_size,
                              hipStream_t stream) {
    const float* prev   = (const float*)d_in[0];
    const int*   edges  = (const int*)d_in[1];
    const float* node   = (const float*)d_in[2];
    const float* edgef  = (const float*)d_in[3];
    const float* status = (const float*)d_in[4];
    const float* W      = (const float*)d_in[5];
    float* out = (float*)d_out;

    const int2* edges2 = (const int2*)edges;

    // ws: slots[N*CAP] u32 | counts[N] i32 | P32[B*N*32] u32
    size_t slots_bytes  = (size_t)N * CAP * sizeof(unsigned);    // 19.2 MB
    size_t counts_bytes = (size_t)N * sizeof(int);               // 0.2 MB
    size_t p_bytes      = (size_t)B * N * 32 * sizeof(unsigned); // 12.8 MB
    size_t need = slots_bytes + counts_bytes + p_bytes;

    if (ws_size >= need) {
        unsigned* slots = (unsigned*)d_ws;
        int* counts = (int*)((char*)d_ws + slots_bytes);
        unsigned* P32 = (unsigned*)((char*)d_ws + slots_bytes + counts_bytes);

        hipMemsetAsync(counts, 0, counts_bytes, stream);
        build_pgemm_fused<<<ECHUNKS * XG + PBLOCKS, 256, 0, stream>>>(
            edges2, status, counts, slots, prev, W, P32);
        gather_final<<<N / 4, 256, 0, stream>>>(
            (const uint4*)P32, counts, slots, node, edgef, out);
    } else {
        hipMemsetAsync(out, 0, (size_t)B * N * D * sizeof(float), stream);
        scatter_kernel<<<(E * 16) / 256, 256, 0, stream>>>(prev, edges2, status, out);
        gemm_relu_kernel<<<(B * N) / 4, 256, 0, stream>>>(out, node, edgef, W);
    }
}